// Round 9
// baseline (341.669 us; speedup 1.0000x reference)
//
#include <hip/hip_runtime.h>
#include <hip/hip_bf16.h>

using bf16 = __bf16;
using bf16x8 = __attribute__((ext_vector_type(8))) __bf16;
using bf16x4 = __attribute__((ext_vector_type(4))) __bf16;
using f32x4  = __attribute__((ext_vector_type(4))) float;
using f32x16 = __attribute__((ext_vector_type(16))) float;

typedef const void __attribute__((address_space(1)))* gas_p;
typedef void __attribute__((address_space(3)))* las_p;

#define GLD16(g, l) __builtin_amdgcn_global_load_lds((gas_p)(const void*)(g), (las_p)(void*)(l), 16, 0, 0)

__device__ __forceinline__ bf16x8 lds_ld8(const void* p) {
  union { uint4 u; bf16x8 v; } c;
  c.u = *(const uint4*)p;
  return c.v;
}
__device__ __forceinline__ bf16x8 g_ld8(const bf16* p) {
  union { uint4 u; bf16x8 v; } c;
  c.u = *(const uint4*)p;
  return c.v;
}
// A-fragment via sigma k-slot permutation: two 4-bf16 chunks at p and p+8
__device__ __forceinline__ bf16x8 g_ld44(const bf16* p) {
  union { uint2 u2[2]; bf16x8 v; } c;
  c.u2[0] = *(const uint2*)p;
  c.u2[1] = *(const uint2*)(p + 8);
  return c.v;
}
// single-instruction 2^x
__device__ __forceinline__ float fexp2(float x) {
  float r; asm("v_exp_f32 %0, %1" : "=v"(r) : "v"(x)); return r;
}
// v_cvt_pk_bf16_f32: dst[15:0]=bf16(lo), dst[31:16]=bf16(hi)
__device__ __forceinline__ unsigned cvtpk(float lo, float hi) {
  unsigned r; asm("v_cvt_pk_bf16_f32 %0, %1, %2" : "=v"(r) : "v"(lo), "v"(hi)); return r;
}

// ---------------- f32 -> bf16 elementwise convert ----------------
__global__ void k_convert(const float* __restrict__ in, bf16* __restrict__ out, int n4) {
  int i = blockIdx.x * blockDim.x + threadIdx.x;
  if (i >= n4) return;
  float4 f = ((const float4*)in)[i];
  bf16x4 o;
  o[0] = (bf16)f.x; o[1] = (bf16)f.y; o[2] = (bf16)f.z; o[3] = (bf16)f.w;
  ((bf16x4*)out)[i] = o;
}

// ---------------- transpose + convert weights: W[K=2048][N] -> Wt[N][2048] bf16 ----------------
__global__ void k_transp(const float* __restrict__ W, bf16* __restrict__ Wt, int N, int rowOff) {
  __shared__ float tile[64][65];
  const int n0 = blockIdx.x * 64, k0 = blockIdx.y * 64;
  const int t = threadIdx.x;
#pragma unroll
  for (int i = 0; i < 16; ++i) {
    int idx = t + i * 256; int r = idx >> 6, c = idx & 63;
    tile[r][c] = W[(size_t)(k0 + r) * N + n0 + c];
  }
  __syncthreads();
#pragma unroll
  for (int i = 0; i < 16; ++i) {
    int idx = t + i * 256; int r = idx >> 6, c = idx & 63;
    Wt[(size_t)(rowOff + n0 + r) * 2048 + k0 + c] = (bf16)tile[c][r];
  }
}

// ---------------- GEMM main loop: C[128x128] += A[128xK] * Bt[128xK]^T, K=2048, BK=32 ----------------
__device__ __forceinline__ void gemm_main(const bf16* __restrict__ A, const bf16* __restrict__ Bt,
                                          int brow, int bcol, int tid, f32x4 (&acc)[4][4],
                                          char* ldsA, char* ldsB) {
  const int lane = tid & 63;
  const int l15 = lane & 15, l4 = lane >> 4;
  const int wid = tid >> 6, wr = wid >> 1, wc = wid & 1;
  const int srow = tid >> 2;
  const int sseg = (tid & 3) ^ (srow & 3);   // pre-swizzled global source (m173 pattern)
  const bf16* ga = A  + (size_t)(brow + srow) * 2048 + sseg * 8;
  const bf16* gb = Bt + (size_t)(bcol + srow) * 2048 + sseg * 8;
  char* la = ldsA + tid * 16;
  char* lb = ldsB + tid * 16;
  const int roff = (l15 & 3) << 4;

  for (int k0 = 0; k0 < 2048; k0 += 32) {
    __syncthreads();
    GLD16(ga + k0, la);
    GLD16(ga + k0 + (size_t)64 * 2048, la + 4096);
    GLD16(gb + k0, lb);
    GLD16(gb + k0 + (size_t)64 * 2048, lb + 4096);
    __syncthreads();
    bf16x8 af[4], bfr[4];
#pragma unroll
    for (int m = 0; m < 4; ++m)
      af[m] = lds_ld8(ldsA + (wr * 64 + m * 16 + l15) * 64 + ((l4 << 4) ^ roff));
#pragma unroll
    for (int n = 0; n < 4; ++n)
      bfr[n] = lds_ld8(ldsB + (wc * 64 + n * 16 + l15) * 64 + ((l4 << 4) ^ roff));
#pragma unroll
    for (int m = 0; m < 4; ++m)
#pragma unroll
      for (int n = 0; n < 4; ++n)
        acc[m][n] = __builtin_amdgcn_mfma_f32_16x16x32_bf16(af[m], bfr[n], acc[m][n], 0, 0, 0);
  }
}

// ---------------- QKV GEMM + RoPE epilogue (V written transposed) ----------------
// Q scale folds 1/sqrt(64) * log2(e) so attention softmax can use exp2 directly.
__global__ __launch_bounds__(256) void k_gemm_qkv(const bf16* __restrict__ A, const bf16* __restrict__ Bt,
    const float* __restrict__ cosT, const float* __restrict__ sinT,
    bf16* __restrict__ Qb, bf16* __restrict__ Kb, bf16* __restrict__ Vt) {
  __shared__ __align__(16) char ldsA[8192];
  __shared__ __align__(16) char ldsB[8192];
  const int tid = threadIdx.x;
  const int brow = blockIdx.x * 128, bcol = blockIdx.y * 128;
  f32x4 zero = {0.f, 0.f, 0.f, 0.f};
  f32x4 acc[4][4];
#pragma unroll
  for (int m = 0; m < 4; ++m)
#pragma unroll
    for (int n = 0; n < 4; ++n) acc[m][n] = zero;

  gemm_main(A, Bt, brow, bcol, tid, acc, ldsA, ldsB);

  const int lane = tid & 63, l15 = lane & 15, l4 = lane >> 4;
  const int wid = tid >> 6, wr = wid >> 1, wc = wid & 1;
  const int base64 = bcol + wc * 64;       // wave-uniform; one head per wave block
  const int rbase  = brow + wr * 64;

  if (base64 < 2048) {                      // Q segment (RoPE + 0.125*log2e scale)
    const int h = base64 >> 6;
#pragma unroll
    for (int m = 0; m < 4; ++m)
#pragma unroll
      for (int r = 0; r < 4; ++r) {
        const int row = rbase + m * 16 + l4 * 4 + r;
        const int b = row >> 11, s = row & 2047;
        float o[4];
#pragma unroll
        for (int n = 0; n < 4; ++n) {
          const int d = n * 16 + l15;
          const float cv = cosT[s * 64 + d], sv = sinT[s * 64 + d];
          const float t = acc[m][n][r], p = acc[m][n ^ 2][r];
          o[n] = (t * cv + ((n < 2) ? -p : p) * sv) * 0.18033688f;
        }
        bf16* dst = Qb + ((size_t)((b * 32 + h) * 2048 + s)) * 64;
#pragma unroll
        for (int n = 0; n < 4; ++n) dst[n * 16 + l15] = (bf16)o[n];
      }
  } else if (base64 < 2560) {               // K segment (RoPE)
    const int h = (base64 - 2048) >> 6;
#pragma unroll
    for (int m = 0; m < 4; ++m)
#pragma unroll
      for (int r = 0; r < 4; ++r) {
        const int row = rbase + m * 16 + l4 * 4 + r;
        const int b = row >> 11, s = row & 2047;
        float o[4];
#pragma unroll
        for (int n = 0; n < 4; ++n) {
          const int d = n * 16 + l15;
          const float cv = cosT[s * 64 + d], sv = sinT[s * 64 + d];
          const float t = acc[m][n][r], p = acc[m][n ^ 2][r];
          o[n] = t * cv + ((n < 2) ? -p : p) * sv;
        }
        bf16* dst = Kb + ((size_t)((b * 8 + h) * 2048 + s)) * 64;
#pragma unroll
        for (int n = 0; n < 4; ++n) dst[n * 16 + l15] = (bf16)o[n];
      }
  } else {                                  // V segment -> transposed Vt[b][hk][d][s]
    const int h = (base64 - 2560) >> 6;
#pragma unroll
    for (int m = 0; m < 4; ++m)
#pragma unroll
      for (int r = 0; r < 4; ++r) {
        const int row = rbase + m * 16 + l4 * 4 + r;
        const int b = row >> 11, s = row & 2047;
#pragma unroll
        for (int n = 0; n < 4; ++n) {
          const int d = n * 16 + l15;
          Vt[((size_t)((b * 8 + h) * 64 + d)) * 2048 + s] = (bf16)acc[m][n][r];
        }
      }
  }
}

// ---------------- Flash attention (causal, GQA), 32x32 swapped-operand ----------------
// R8 tile body (verified): sc = mfma_32x32x16(K,Q); lane holds one q-row split
// across lane<->lane^32; sigma k-slot permutation makes the PV P-fragment the
// lane's OWN registers. New in R9: 2 waves/block split kv tiles by parity
// (equal-length waves, 8 blocks/CU steady), sequential chunk pair (63-a, a),
// tree reductions, lane-local lsum (row-sum deferred to merge).
__device__ __forceinline__ void attn_chunk(const bf16* __restrict__ Qb, const bf16* kbase, const bf16* vbase,
                                           int qoff, int q0, int nf, int w, int l31, int hi,
                                           float& m, float& lsum, f32x16 (&o)[2]) {
  const f32x16 z16 = {0,0,0,0,0,0,0,0,0,0,0,0,0,0,0,0};
  o[0] = z16; o[1] = z16;
  m = -3.0e38f; lsum = 0.f;
  const bf16* qbase = Qb + ((size_t)(qoff + q0 + l31)) * 64 + hi * 8;
  bf16x8 bq[4];
#pragma unroll
  for (int dc = 0; dc < 4; ++dc) bq[dc] = g_ld8(qbase + dc * 16);

  for (int kt = w; kt <= nf; kt += 2) {
    const int kv0 = kt * 64;
    // ---- K A-fragments: row = kv = kv0+kvh*32+l31, k = d ----
    bf16x8 ak[2][4];
#pragma unroll
    for (int kvh = 0; kvh < 2; ++kvh)
#pragma unroll
      for (int dc = 0; dc < 4; ++dc)
        ak[kvh][dc] = g_ld8(kbase + (size_t)(kv0 + kvh * 32) * 64 + dc * 16);
    f32x16 sc[2];
    __builtin_amdgcn_s_setprio(1);
#pragma unroll
    for (int kvh = 0; kvh < 2; ++kvh) {
      sc[kvh] = __builtin_amdgcn_mfma_f32_32x32x16_bf16(ak[kvh][0], bq[0], z16, 0, 0, 0);
#pragma unroll
      for (int dc = 1; dc < 4; ++dc)
        sc[kvh] = __builtin_amdgcn_mfma_f32_32x32x16_bf16(ak[kvh][dc], bq[dc], sc[kvh], 0, 0, 0);
    }
    __builtin_amdgcn_s_setprio(0);
    // ---- V^T A-fragments (sigma layout) ----
    bf16x8 av[2][4];
#pragma unroll
    for (int dh = 0; dh < 2; ++dh)
#pragma unroll
      for (int cc = 0; cc < 4; ++cc)
        av[dh][cc] = g_ld44(vbase + (size_t)dh * 65536 + kv0 + cc * 16);

    if (kt == nf) {   // diagonal tile: mask kv > q
      const int q = q0 + l31;
#pragma unroll
      for (int kvh = 0; kvh < 2; ++kvh)
#pragma unroll
        for (int r = 0; r < 16; ++r) {
          const int kv = kv0 + kvh * 32 + (r & 3) + 8 * (r >> 2) + 4 * hi;
          if (kv > q) sc[kvh][r] = -3.0e30f;
        }
    }
    // ---- softmax: tree max + one bpermute ----
    float t[16];
#pragma unroll
    for (int i = 0; i < 16; ++i) t[i] = fmaxf(sc[0][i], sc[1][i]);
#pragma unroll
    for (int st = 8; st >= 1; st >>= 1)
#pragma unroll
      for (int i = 0; i < st; ++i) t[i] = fmaxf(t[i], t[i + st]);
    float mx = fmaxf(t[0], __shfl_xor(t[0], 32));
    // defer-max (T13): rescale only if max grew by > 11.5 (log2 units)
    if (!__all(mx <= m + 11.5f)) {
      const float mn = fmaxf(m, mx);
      const float corr = fexp2(m - mn);
      m = mn;
      lsum *= corr;
#pragma unroll
      for (int r = 0; r < 16; ++r) { o[0][r] *= corr; o[1][r] *= corr; }
    }
#pragma unroll
    for (int kvh = 0; kvh < 2; ++kvh)
#pragma unroll
      for (int r = 0; r < 16; ++r) sc[kvh][r] = fexp2(sc[kvh][r] - m);
    // ---- PV: P B-fragment = own sc registers packed (sigma) ----
#pragma unroll
    for (int kvh = 0; kvh < 2; ++kvh) {
#pragma unroll
      for (int s = 0; s < 2; ++s) {
        union { unsigned u[4]; bf16x8 v; } f;
#pragma unroll
        for (int tt = 0; tt < 4; ++tt)
          f.u[tt] = cvtpk(sc[kvh][s * 8 + 2 * tt], sc[kvh][s * 8 + 2 * tt + 1]);
        __builtin_amdgcn_s_setprio(1);
#pragma unroll
        for (int dh = 0; dh < 2; ++dh)
          o[dh] = __builtin_amdgcn_mfma_f32_32x32x16_bf16(av[dh][kvh * 2 + s], f.v, o[dh], 0, 0, 0);
        __builtin_amdgcn_s_setprio(0);
      }
    }
    // ---- lane-local sum tree (off PV critical path; row-sum at merge) ----
    float u[16];
#pragma unroll
    for (int i = 0; i < 16; ++i) u[i] = sc[0][i] + sc[1][i];
#pragma unroll
    for (int st = 8; st >= 1; st >>= 1)
#pragma unroll
      for (int i = 0; i < st; ++i) u[i] += u[i + st];
    lsum += u[0];
  }
}

__global__ __launch_bounds__(128) void k_attn(const bf16* __restrict__ Qb, const bf16* __restrict__ Kb,
                                              const bf16* __restrict__ Vt, bf16* __restrict__ ctx) {
  __shared__ __align__(16) float mslot[2048 + 128];  // wave1 partial: o[32][64] + m[64] + l[64]
  __shared__ __align__(16) char tbuf[4096];          // wave0 epilogue transpose
  const int tid = threadIdx.x, lane = tid & 63, w = tid >> 6;  // w in {0,1}
  const int l31 = lane & 31, hi = lane >> 5;
  // XCD-aware: XCD = p&7 owns 8 contiguous bh values
  const int p = (int)blockIdx.x;
  const int y = (p & 7) * 8 + ((p >> 3) & 7);   // bh
  const int a = p >> 6;                          // pair index 0..31
  const int b = y >> 5, h = y & 31, hk = h >> 2;
  const int qoff = (b * 32 + h) * 2048;

  const bf16* kbase = Kb + ((size_t)((b * 8 + hk) * 2048) + l31) * 64 + hi * 8;
  const bf16* vbase = Vt + ((size_t)((b * 8 + hk) * 64) + l31) * 2048 + hi * 4;  // sigma base

  float m, lsum;
  f32x16 o[2];

#pragma unroll
  for (int half = 0; half < 2; ++half) {
    const int c = half ? a : 63 - a;           // long chunk first
    const int q0 = c * 32, nf = c >> 1;
    attn_chunk(Qb, kbase, vbase, qoff, q0, nf, w, l31, hi, m, lsum, o);
    // ---- merge wave1 partial into wave0, wave0 stores ----
    __syncthreads();
    if (w == 1) {
#pragma unroll
      for (int dh = 0; dh < 2; ++dh)
#pragma unroll
        for (int r = 0; r < 16; ++r) mslot[(dh * 16 + r) * 64 + lane] = o[dh][r];
      mslot[2048 + lane] = m;
      mslot[2112 + lane] = lsum;
    }
    __syncthreads();
    if (w == 0) {
      const float m2 = mslot[2048 + lane], l2 = mslot[2112 + lane];
      const float M = fmaxf(m, m2);
      const float ca = fexp2(m - M), cb = fexp2(m2 - M);
      float ll = lsum * ca + l2 * cb;
      ll += __shfl_xor(ll, 32);                 // row total across lane^32
      const float inv = 1.0f / ll;
      const int sw = (l31 & 7) << 4;
#pragma unroll
      for (int dh = 0; dh < 2; ++dh)
#pragma unroll
        for (int r = 0; r < 16; r += 2) {
          const float v0 = (o[dh][r]     * ca + mslot[(dh * 16 + r)     * 64 + lane] * cb) * inv;
          const float v1 = (o[dh][r + 1] * ca + mslot[(dh * 16 + r + 1) * 64 + lane] * cb) * inv;
          const unsigned wdv = cvtpk(v0, v1);
          const int d = dh * 32 + (r & 3) + 8 * (r >> 2) + 4 * hi;
          *(unsigned*)(tbuf + l31 * 128 + ((d * 2) ^ sw)) = wdv;
        }
#pragma unroll
      for (int j = 0; j < 4; ++j) {
        const int off = hi * 16 + j * 32;
        uint4 val = *(const uint4*)(tbuf + l31 * 128 + (off ^ sw));
        *(uint4*)(ctx + ((size_t)(b * 2048 + q0 + l31)) * 2048 + h * 64 + off / 2) = val;
      }
    }
    // next half's barrier (top of loop) protects mslot/tbuf reuse
  }
}

// ---------------- Output GEMM: ctx @ Wo -> f32 ----------------
__global__ __launch_bounds__(256) void k_gemm_out(const bf16* __restrict__ A, const bf16* __restrict__ Bt,
                                                  float* __restrict__ out) {
  __shared__ __align__(16) char ldsA[8192];
  __shared__ __align__(16) char ldsB[8192];
  const int tid = threadIdx.x;
  const int brow = blockIdx.x * 128, bcol = blockIdx.y * 128;
  f32x4 zero = {0.f, 0.f, 0.f, 0.f};
  f32x4 acc[4][4];
#pragma unroll
  for (int m = 0; m < 4; ++m)
#pragma unroll
    for (int n = 0; n < 4; ++n) acc[m][n] = zero;

  gemm_main(A, Bt, brow, bcol, tid, acc, ldsA, ldsB);

  const int lane = tid & 63, l15 = lane & 15, l4 = lane >> 4;
  const int wid = tid >> 6, wr = wid >> 1, wc = wid & 1;
#pragma unroll
  for (int m = 0; m < 4; ++m)
#pragma unroll
    for (int r = 0; r < 4; ++r) {
      const int row = brow + wr * 64 + m * 16 + l4 * 4 + r;
      float* dst = out + (size_t)row * 2048 + bcol + wc * 64;
#pragma unroll
      for (int n = 0; n < 4; ++n) dst[n * 16 + l15] = acc[m][n][r];
    }
}

extern "C" void kernel_launch(void* const* d_in, const int* in_sizes, int n_in,
                              void* d_out, int out_size, void* d_ws, size_t ws_size,
                              hipStream_t stream) {
  (void)in_sizes; (void)n_in; (void)out_size;
  if (ws_size < (size_t)79691776) return;   // need ~76 MB scratch
  const float* x    = (const float*)d_in[0];
  // d_in[1] = mask (causal, hardcoded)
  const float* cosT = (const float*)d_in[2];
  const float* sinT = (const float*)d_in[3];
  const float* Wq   = (const float*)d_in[4];
  const float* Wk   = (const float*)d_in[5];
  const float* Wv   = (const float*)d_in[6];
  const float* Wo   = (const float*)d_in[7];
  char* ws = (char*)d_ws;
  bf16* xb   = (bf16*)(ws + 0);            // [4096][2048]
  bf16* wqkv = (bf16*)(ws + 16777216);     // [3072][2048]  (Wq^T | Wk^T | Wv^T)
  bf16* wo_t = (bf16*)(ws + 29360128);     // [2048][2048]
  bf16* Qb   = (bf16*)(ws + 37748736);     // [2][32][2048][64]
  bf16* Kb   = (bf16*)(ws + 54525952);     // [2][8][2048][64]
  bf16* Vt   = (bf16*)(ws + 58720256);     // [2][8][64][2048]  (transposed V)
  bf16* ctxb = (bf16*)(ws + 62914560);     // [4096][2048]
  float* out = (float*)d_out;

  k_convert<<<8192, 256, 0, stream>>>(x, xb, 2097152);
  k_transp<<<dim3(32, 32), 256, 0, stream>>>(Wq, wqkv, 2048, 0);
  k_transp<<<dim3(8, 32),  256, 0, stream>>>(Wk, wqkv, 512, 2048);
  k_transp<<<dim3(8, 32),  256, 0, stream>>>(Wv, wqkv, 512, 2560);
  k_transp<<<dim3(32, 32), 256, 0, stream>>>(Wo, wo_t, 2048, 0);
  k_gemm_qkv<<<dim3(32, 24), 256, 0, stream>>>(xb, wqkv, cosT, sinT, Qb, Kb, Vt);
  k_attn<<<2048, 128, 0, stream>>>(Qb, Kb, Vt, ctxb);
  k_gemm_out<<<dim3(32, 16), 256, 0, stream>>>(ctxb, wo_t, out);
}

// Round 10
// 266.303 us; speedup vs baseline: 1.2830x; 1.2830x over previous
//
#include <hip/hip_runtime.h>
#include <hip/hip_bf16.h>

using bf16 = __bf16;
using bf16x8 = __attribute__((ext_vector_type(8))) __bf16;
using bf16x4 = __attribute__((ext_vector_type(4))) __bf16;
using f32x4  = __attribute__((ext_vector_type(4))) float;
using f32x16 = __attribute__((ext_vector_type(16))) float;

typedef const void __attribute__((address_space(1)))* gas_p;
typedef void __attribute__((address_space(3)))* las_p;

#define GLD16(g, l) __builtin_amdgcn_global_load_lds((gas_p)(const void*)(g), (las_p)(void*)(l), 16, 0, 0)

__device__ __forceinline__ bf16x8 lds_ld8(const void* p) {
  union { uint4 u; bf16x8 v; } c;
  c.u = *(const uint4*)p;
  return c.v;
}
__device__ __forceinline__ bf16x8 g_ld8(const bf16* p) {
  union { uint4 u; bf16x8 v; } c;
  c.u = *(const uint4*)p;
  return c.v;
}
// single-instruction 2^x
__device__ __forceinline__ float fexp2(float x) {
  float r; asm("v_exp_f32 %0, %1" : "=v"(r) : "v"(x)); return r;
}
// v_cvt_pk_bf16_f32: dst[15:0]=bf16(lo), dst[31:16]=bf16(hi)
__device__ __forceinline__ unsigned cvtpk(float lo, float hi) {
  unsigned r; asm("v_cvt_pk_bf16_f32 %0, %1, %2" : "=v"(r) : "v"(lo), "v"(hi)); return r;
}

// ---------------- f32 -> bf16 elementwise convert ----------------
__global__ void k_convert(const float* __restrict__ in, bf16* __restrict__ out, int n4) {
  int i = blockIdx.x * blockDim.x + threadIdx.x;
  if (i >= n4) return;
  float4 f = ((const float4*)in)[i];
  bf16x4 o;
  o[0] = (bf16)f.x; o[1] = (bf16)f.y; o[2] = (bf16)f.z; o[3] = (bf16)f.w;
  ((bf16x4*)out)[i] = o;
}

// ---------------- transpose + convert weights: W[K=2048][N] -> Wt[N][2048] bf16 ----------------
__global__ void k_transp(const float* __restrict__ W, bf16* __restrict__ Wt, int N, int rowOff) {
  __shared__ float tile[64][65];
  const int n0 = blockIdx.x * 64, k0 = blockIdx.y * 64;
  const int t = threadIdx.x;
#pragma unroll
  for (int i = 0; i < 16; ++i) {
    int idx = t + i * 256; int r = idx >> 6, c = idx & 63;
    tile[r][c] = W[(size_t)(k0 + r) * N + n0 + c];
  }
  __syncthreads();
#pragma unroll
  for (int i = 0; i < 16; ++i) {
    int idx = t + i * 256; int r = idx >> 6, c = idx & 63;
    Wt[(size_t)(rowOff + n0 + r) * 2048 + k0 + c] = (bf16)tile[c][r];
  }
}

// ---------------- GEMM main loop: C[128x128] += A[128xK] * Bt[128xK]^T, K=2048, BK=32 ----------------
__device__ __forceinline__ void gemm_main(const bf16* __restrict__ A, const bf16* __restrict__ Bt,
                                          int brow, int bcol, int tid, f32x4 (&acc)[4][4],
                                          char* ldsA, char* ldsB) {
  const int lane = tid & 63;
  const int l15 = lane & 15, l4 = lane >> 4;
  const int wid = tid >> 6, wr = wid >> 1, wc = wid & 1;
  const int srow = tid >> 2;
  const int sseg = (tid & 3) ^ (srow & 3);   // pre-swizzled global source (m173 pattern)
  const bf16* ga = A  + (size_t)(brow + srow) * 2048 + sseg * 8;
  const bf16* gb = Bt + (size_t)(bcol + srow) * 2048 + sseg * 8;
  char* la = ldsA + tid * 16;
  char* lb = ldsB + tid * 16;
  const int roff = (l15 & 3) << 4;

  for (int k0 = 0; k0 < 2048; k0 += 32) {
    __syncthreads();
    GLD16(ga + k0, la);
    GLD16(ga + k0 + (size_t)64 * 2048, la + 4096);
    GLD16(gb + k0, lb);
    GLD16(gb + k0 + (size_t)64 * 2048, lb + 4096);
    __syncthreads();
    bf16x8 af[4], bfr[4];
#pragma unroll
    for (int m = 0; m < 4; ++m)
      af[m] = lds_ld8(ldsA + (wr * 64 + m * 16 + l15) * 64 + ((l4 << 4) ^ roff));
#pragma unroll
    for (int n = 0; n < 4; ++n)
      bfr[n] = lds_ld8(ldsB + (wc * 64 + n * 16 + l15) * 64 + ((l4 << 4) ^ roff));
#pragma unroll
    for (int m = 0; m < 4; ++m)
#pragma unroll
      for (int n = 0; n < 4; ++n)
        acc[m][n] = __builtin_amdgcn_mfma_f32_16x16x32_bf16(af[m], bfr[n], acc[m][n], 0, 0, 0);
  }
}

// ---------------- QKV GEMM + RoPE epilogue (V written transposed + pi-permuted) ----------------
// Q scale folds 1/sqrt(64) * log2(e) so attention softmax can use exp2 directly.
// V is written as Vt[b][hk][d][pi(s)] where pi swaps bits 2<->3 of s, so the
// attention PV A-fragment (sigma k-slot order) is 16 contiguous bytes.
__global__ __launch_bounds__(256) void k_gemm_qkv(const bf16* __restrict__ A, const bf16* __restrict__ Bt,
    const float* __restrict__ cosT, const float* __restrict__ sinT,
    bf16* __restrict__ Qb, bf16* __restrict__ Kb, bf16* __restrict__ Vt) {
  __shared__ __align__(16) char ldsA[8192];
  __shared__ __align__(16) char ldsB[8192];
  const int tid = threadIdx.x;
  const int brow = blockIdx.x * 128, bcol = blockIdx.y * 128;
  f32x4 zero = {0.f, 0.f, 0.f, 0.f};
  f32x4 acc[4][4];
#pragma unroll
  for (int m = 0; m < 4; ++m)
#pragma unroll
    for (int n = 0; n < 4; ++n) acc[m][n] = zero;

  gemm_main(A, Bt, brow, bcol, tid, acc, ldsA, ldsB);

  const int lane = tid & 63, l15 = lane & 15, l4 = lane >> 4;
  const int wid = tid >> 6, wr = wid >> 1, wc = wid & 1;
  const int base64 = bcol + wc * 64;       // wave-uniform; one head per wave block
  const int rbase  = brow + wr * 64;

  if (base64 < 2048) {                      // Q segment (RoPE + 0.125*log2e scale)
    const int h = base64 >> 6;
#pragma unroll
    for (int m = 0; m < 4; ++m)
#pragma unroll
      for (int r = 0; r < 4; ++r) {
        const int row = rbase + m * 16 + l4 * 4 + r;
        const int b = row >> 11, s = row & 2047;
        float o[4];
#pragma unroll
        for (int n = 0; n < 4; ++n) {
          const int d = n * 16 + l15;
          const float cv = cosT[s * 64 + d], sv = sinT[s * 64 + d];
          const float t = acc[m][n][r], p = acc[m][n ^ 2][r];
          o[n] = (t * cv + ((n < 2) ? -p : p) * sv) * 0.18033688f;
        }
        bf16* dst = Qb + ((size_t)((b * 32 + h) * 2048 + s)) * 64;
#pragma unroll
        for (int n = 0; n < 4; ++n) dst[n * 16 + l15] = (bf16)o[n];
      }
  } else if (base64 < 2560) {               // K segment (RoPE)
    const int h = (base64 - 2048) >> 6;
#pragma unroll
    for (int m = 0; m < 4; ++m)
#pragma unroll
      for (int r = 0; r < 4; ++r) {
        const int row = rbase + m * 16 + l4 * 4 + r;
        const int b = row >> 11, s = row & 2047;
        float o[4];
#pragma unroll
        for (int n = 0; n < 4; ++n) {
          const int d = n * 16 + l15;
          const float cv = cosT[s * 64 + d], sv = sinT[s * 64 + d];
          const float t = acc[m][n][r], p = acc[m][n ^ 2][r];
          o[n] = t * cv + ((n < 2) ? -p : p) * sv;
        }
        bf16* dst = Kb + ((size_t)((b * 8 + h) * 2048 + s)) * 64;
#pragma unroll
        for (int n = 0; n < 4; ++n) dst[n * 16 + l15] = (bf16)o[n];
      }
  } else {                                  // V segment -> Vt[b][hk][d][pi(s)]
    const int h = (base64 - 2560) >> 6;
#pragma unroll
    for (int m = 0; m < 4; ++m)
#pragma unroll
      for (int r = 0; r < 4; ++r) {
        const int row = rbase + m * 16 + l4 * 4 + r;
        const int b = row >> 11, s = row & 2047;
        const int ps = (s & ~12) | ((s & 4) << 1) | ((s & 8) >> 1);  // swap bits 2,3
#pragma unroll
        for (int n = 0; n < 4; ++n) {
          const int d = n * 16 + l15;
          Vt[((size_t)((b * 8 + h) * 64 + d)) * 2048 + ps] = (bf16)acc[m][n][r];
        }
      }
  }
}

// ---------------- Flash attention (causal, GQA), 32x32 sigma body + LDS staging ----------------
// Diagnosis R9: per-lane scattered MFMA fragment loads amplify L2 traffic ~4-6x
// (~32 lines per VMEM instr) -> L2-BW-bound. Fix: 4-wave blocks share each
// 64-kv tile via double-buffered LDS (coalesced global reads, reg-staged with
// XOR-swizzled rows). The verified 32x32 swapped-operand sigma body is kept;
// fragments now come from ds_read_b128 (V pre-permuted by pi in k_gemm_qkv).
__global__ __launch_bounds__(256) void k_attn(const bf16* __restrict__ Qb, const bf16* __restrict__ Kb,
                                              const bf16* __restrict__ Vtp, bf16* __restrict__ ctx) {
  __shared__ __align__(16) char kvb[2][16384];  // [buf][128 rows x 128B]; rows 0-63 K, 64-127 V^T(pi)
  const int tid = threadIdx.x, lane = tid & 63, w = tid >> 6;
  const int l31 = lane & 31, hi = lane >> 5;
  // XCD-aware: XCD = p&7 owns 8 contiguous bh; heavy q-blocks dispatched first
  const int p = (int)blockIdx.x;
  const int y = (p & 7) * 8 + ((p >> 3) & 7);   // bh
  const int c = 15 - (p >> 6);                   // q-block 0..15, heavy first
  const int b = y >> 5, h = y & 31, hk = h >> 2;
  const int q0 = c * 128 + w * 32;               // this wave's 32 q rows
  const int nf = (q0 + 31) >> 6;                 // wave's diagonal kv tile
  const int nt = 2 * c + 2;                      // kv tiles staged by the block

  // staging: thread t covers row srow(+32 per round), 16B segment sseg
  const int srow = tid >> 3, sseg = tid & 7;
  const bf16* kS = Kb  + ((size_t)((b * 8 + hk) * 2048)) * 64;
  const bf16* vS = Vtp + ((size_t)((b * 8 + hk) * 64)) * 2048;

  const bf16* qbase = Qb + ((size_t)((b * 32 + h) * 2048 + q0 + l31)) * 64 + hi * 8;
  bf16x8 bq[4];
#pragma unroll
  for (int dc = 0; dc < 4; ++dc) bq[dc] = g_ld8(qbase + dc * 16);

  const f32x16 z16 = {0,0,0,0,0,0,0,0,0,0,0,0,0,0,0,0};
  f32x16 o[2] = {z16, z16};
  float m = -3.0e38f, lsum = 0.f;
  const int sz = (l31 & 7) << 4;       // fragment-read swizzle (row&7 == l31&7)
  const int wsz = (srow & 7) << 4;     // staging-write swizzle

  uint4 st[4];
  auto stage_load = [&](int kv0) {
#pragma unroll
    for (int r4 = 0; r4 < 4; ++r4) {
      const int row = srow + (r4 & 1) * 32;
      const bf16* g = (r4 < 2) ? (kS + (size_t)(kv0 + row) * 64 + sseg * 8)
                               : (vS + (size_t)row * 2048 + kv0 + sseg * 8);
      st[r4] = *(const uint4*)g;
    }
  };
  auto stage_write = [&](char* buf) {
#pragma unroll
    for (int r4 = 0; r4 < 4; ++r4)
      *(uint4*)(buf + (srow + r4 * 32) * 128 + ((sseg * 16) ^ wsz)) = st[r4];
  };

  stage_load(0);
  stage_write(kvb[0]);
  __syncthreads();

  for (int kt = 0; kt < nt; ++kt) {
    char* cur = kvb[kt & 1];
    if (kt + 1 < nt) stage_load((kt + 1) * 64);   // issue early, land under compute
    if (kt <= nf) {
      const int kv0 = kt * 64;
      // ---- QK: sc = mfma(K, Q), K fragments from LDS ----
      f32x16 sc[2];
      __builtin_amdgcn_s_setprio(1);
#pragma unroll
      for (int kvh = 0; kvh < 2; ++kvh) {
        const int row = kvh * 32 + l31;
        bf16x8 a0 = lds_ld8(cur + row * 128 + ((hi * 16) ^ sz));
        sc[kvh] = __builtin_amdgcn_mfma_f32_32x32x16_bf16(a0, bq[0], z16, 0, 0, 0);
#pragma unroll
        for (int dc = 1; dc < 4; ++dc) {
          bf16x8 ad = lds_ld8(cur + row * 128 + ((dc * 32 + hi * 16) ^ sz));
          sc[kvh] = __builtin_amdgcn_mfma_f32_32x32x16_bf16(ad, bq[dc], sc[kvh], 0, 0, 0);
        }
      }
      __builtin_amdgcn_s_setprio(0);
      if (kt == nf) {   // diagonal tile: mask kv > q
        const int q = q0 + l31;
#pragma unroll
        for (int kvh = 0; kvh < 2; ++kvh)
#pragma unroll
          for (int r = 0; r < 16; ++r) {
            const int kv = kv0 + kvh * 32 + (r & 3) + 8 * (r >> 2) + 4 * hi;
            if (kv > q) sc[kvh][r] = -3.0e30f;
          }
      }
      // ---- softmax: tree max + one cross shuffle ----
      float t[16];
#pragma unroll
      for (int i = 0; i < 16; ++i) t[i] = fmaxf(sc[0][i], sc[1][i]);
#pragma unroll
      for (int stp = 8; stp >= 1; stp >>= 1)
#pragma unroll
        for (int i = 0; i < stp; ++i) t[i] = fmaxf(t[i], t[i + stp]);
      float mx = fmaxf(t[0], __shfl_xor(t[0], 32));
      // defer-max (T13): rescale only if max grew by > 11.5 (log2 units)
      if (!__all(mx <= m + 11.5f)) {
        const float mn = fmaxf(m, mx);
        const float corr = fexp2(m - mn);
        m = mn;
        lsum *= corr;
#pragma unroll
        for (int r = 0; r < 16; ++r) { o[0][r] *= corr; o[1][r] *= corr; }
      }
#pragma unroll
      for (int kvh = 0; kvh < 2; ++kvh)
#pragma unroll
        for (int r = 0; r < 16; ++r) sc[kvh][r] = fexp2(sc[kvh][r] - m);
      // ---- PV: P B-fragment = own sc registers (sigma); V(pi) from LDS ----
#pragma unroll
      for (int kvh = 0; kvh < 2; ++kvh)
#pragma unroll
        for (int s = 0; s < 2; ++s) {
          union { unsigned u[4]; bf16x8 v; } f;
#pragma unroll
          for (int tt = 0; tt < 4; ++tt)
            f.u[tt] = cvtpk(sc[kvh][s * 8 + 2 * tt], sc[kvh][s * 8 + 2 * tt + 1]);
          const int cc = kvh * 2 + s;
          __builtin_amdgcn_s_setprio(1);
#pragma unroll
          for (int dh = 0; dh < 2; ++dh) {
            const int row = 64 + dh * 32 + l31;
            bf16x8 av = lds_ld8(cur + row * 128 + ((cc * 32 + hi * 16) ^ sz));
            o[dh] = __builtin_amdgcn_mfma_f32_32x32x16_bf16(av, f.v, o[dh], 0, 0, 0);
          }
          __builtin_amdgcn_s_setprio(0);
        }
      // ---- lane-local sum tree ----
      float u[16];
#pragma unroll
      for (int i = 0; i < 16; ++i) u[i] = sc[0][i] + sc[1][i];
#pragma unroll
      for (int stp = 8; stp >= 1; stp >>= 1)
#pragma unroll
        for (int i = 0; i < stp; ++i) u[i] += u[i + stp];
      lsum += u[0];
    }
    if (kt + 1 < nt) stage_write(kvb[(kt + 1) & 1]);
    __syncthreads();
  }

  // ---- epilogue: normalize, transpose via per-wave LDS slice, store ----
  float ll = lsum + __shfl_xor(lsum, 32);
  const float inv = 1.0f / ll;
  char* tb = kvb[0] + w * 4096;   // free after final barrier
#pragma unroll
  for (int dh = 0; dh < 2; ++dh)
#pragma unroll
    for (int r = 0; r < 16; r += 2) {
      const unsigned wdv = cvtpk(o[dh][r] * inv, o[dh][r + 1] * inv);
      const int d = dh * 32 + (r & 3) + 8 * (r >> 2) + 4 * hi;
      *(unsigned*)(tb + l31 * 128 + ((d * 2) ^ sz)) = wdv;
    }
#pragma unroll
  for (int j = 0; j < 4; ++j) {
    const int off = hi * 16 + j * 32;
    uint4 val = *(const uint4*)(tb + l31 * 128 + (off ^ sz));
    *(uint4*)(ctx + ((size_t)(b * 2048 + q0 + l31)) * 2048 + h * 64 + off / 2) = val;
  }
}

// ---------------- Output GEMM: ctx @ Wo -> f32 ----------------
__global__ __launch_bounds__(256) void k_gemm_out(const bf16* __restrict__ A, const bf16* __restrict__ Bt,
                                                  float* __restrict__ out) {
  __shared__ __align__(16) char ldsA[8192];
  __shared__ __align__(16) char ldsB[8192];
  const int tid = threadIdx.x;
  const int brow = blockIdx.x * 128, bcol = blockIdx.y * 128;
  f32x4 zero = {0.f, 0.f, 0.f, 0.f};
  f32x4 acc[4][4];
#pragma unroll
  for (int m = 0; m < 4; ++m)
#pragma unroll
    for (int n = 0; n < 4; ++n) acc[m][n] = zero;

  gemm_main(A, Bt, brow, bcol, tid, acc, ldsA, ldsB);

  const int lane = tid & 63, l15 = lane & 15, l4 = lane >> 4;
  const int wid = tid >> 6, wr = wid >> 1, wc = wid & 1;
#pragma unroll
  for (int m = 0; m < 4; ++m)
#pragma unroll
    for (int r = 0; r < 4; ++r) {
      const int row = brow + wr * 64 + m * 16 + l4 * 4 + r;
      float* dst = out + (size_t)row * 2048 + bcol + wc * 64;
#pragma unroll
      for (int n = 0; n < 4; ++n) dst[n * 16 + l15] = acc[m][n][r];
    }
}

extern "C" void kernel_launch(void* const* d_in, const int* in_sizes, int n_in,
                              void* d_out, int out_size, void* d_ws, size_t ws_size,
                              hipStream_t stream) {
  (void)in_sizes; (void)n_in; (void)out_size;
  if (ws_size < (size_t)79691776) return;   // need ~76 MB scratch
  const float* x    = (const float*)d_in[0];
  // d_in[1] = mask (causal, hardcoded)
  const float* cosT = (const float*)d_in[2];
  const float* sinT = (const float*)d_in[3];
  const float* Wq   = (const float*)d_in[4];
  const float* Wk   = (const float*)d_in[5];
  const float* Wv   = (const float*)d_in[6];
  const float* Wo   = (const float*)d_in[7];
  char* ws = (char*)d_ws;
  bf16* xb   = (bf16*)(ws + 0);            // [4096][2048]
  bf16* wqkv = (bf16*)(ws + 16777216);     // [3072][2048]  (Wq^T | Wk^T | Wv^T)
  bf16* wo_t = (bf16*)(ws + 29360128);     // [2048][2048]
  bf16* Qb   = (bf16*)(ws + 37748736);     // [2][32][2048][64]
  bf16* Kb   = (bf16*)(ws + 54525952);     // [2][8][2048][64]
  bf16* Vt   = (bf16*)(ws + 58720256);     // [2][8][64][2048]  (transposed V, pi-permuted)
  bf16* ctxb = (bf16*)(ws + 62914560);     // [4096][2048]
  float* out = (float*)d_out;

  k_convert<<<8192, 256, 0, stream>>>(x, xb, 2097152);
  k_transp<<<dim3(32, 32), 256, 0, stream>>>(Wq, wqkv, 2048, 0);
  k_transp<<<dim3(8, 32),  256, 0, stream>>>(Wk, wqkv, 512, 2048);
  k_transp<<<dim3(8, 32),  256, 0, stream>>>(Wv, wqkv, 512, 2560);
  k_transp<<<dim3(32, 32), 256, 0, stream>>>(Wo, wo_t, 2048, 0);
  k_gemm_qkv<<<dim3(32, 24), 256, 0, stream>>>(xb, wqkv, cosT, sinT, Qb, Kb, Vt);
  k_attn<<<1024, 256, 0, stream>>>(Qb, Kb, Vt, ctxb);
  k_gemm_out<<<dim3(32, 16), 256, 0, stream>>>(ctxb, wo_t, out);
}